// Round 1
// baseline (3596.230 us; speedup 1.0000x reference)
//
#include <hip/hip_runtime.h>
#include <math.h>

#define NUM_ENT   100000
#define NUM_REL   50
#define NUM_EDGES 200000
#define NNZ       1000000
#define DIM       128
#define BATCH     4096

// ws layout (in floats): Xl | Xe | Xv
#define XL_OFF 0
#define XE_OFF (NUM_ENT * DIM)                    // 12.8M floats
#define XV_OFF (XE_OFF + NUM_EDGES * DIM)         // +25.6M floats

// ---------------------------------------------------------------------------
// Kernel 1: Y = X @ W^T + b   (raw linear output; lorentz applied in kernel 2)
// Block: 256 threads, tile = 64 rows x 128 cols, K staged in 2 chunks of 64.
__global__ __launch_bounds__(256) void k_gemm(const float* __restrict__ X,
                                              const float* __restrict__ W,
                                              const float* __restrict__ bias,
                                              float* __restrict__ Y) {
    __shared__ float Xs[64][68];    // Xs[k_local][row]   (transposed)
    __shared__ float Ws[64][132];   // Ws[k_local][col j] (transposed W)
    const int t = threadIdx.x;
    const int row0 = blockIdx.x * 64;
    const float4* X4 = (const float4*)X;
    const float4* W4 = (const float4*)W;
    const int tx = t & 15, ty = t >> 4;
    const int j0 = tx * 8;          // 8 cols per thread
    const int r0 = ty * 4;          // 4 rows per thread

    float acc[4][8];
#pragma unroll
    for (int r = 0; r < 4; ++r)
#pragma unroll
        for (int j = 0; j < 8; ++j) acc[r][j] = 0.f;

    for (int kk = 0; kk < 128; kk += 64) {
        // stage X chunk: 64 rows x 64 k  (1024 float4)
#pragma unroll
        for (int i = 0; i < 4; ++i) {
            int q = t + 256 * i;           // 0..1023
            int r = q >> 4, k4 = q & 15;
            int gr = row0 + r;
            float4 v = make_float4(0.f, 0.f, 0.f, 0.f);
            if (gr < NUM_ENT) v = X4[gr * 32 + (kk >> 2) + k4];
            Xs[k4 * 4 + 0][r] = v.x; Xs[k4 * 4 + 1][r] = v.y;
            Xs[k4 * 4 + 2][r] = v.z; Xs[k4 * 4 + 3][r] = v.w;
        }
        // stage W chunk: 128 j x 64 k  (2048 float4)
#pragma unroll
        for (int i = 0; i < 8; ++i) {
            int q = t + 256 * i;           // 0..2047
            int j = q >> 4, k4 = q & 15;
            float4 v = W4[j * 32 + (kk >> 2) + k4];
            Ws[k4 * 4 + 0][j] = v.x; Ws[k4 * 4 + 1][j] = v.y;
            Ws[k4 * 4 + 2][j] = v.z; Ws[k4 * 4 + 3][j] = v.w;
        }
        __syncthreads();
#pragma unroll 8
        for (int k = 0; k < 64; ++k) {
            float4 xv = *(const float4*)&Xs[k][r0];
            float4 wa = *(const float4*)&Ws[k][j0];
            float4 wb = *(const float4*)&Ws[k][j0 + 4];
            float xr[4] = {xv.x, xv.y, xv.z, xv.w};
            float wv[8] = {wa.x, wa.y, wa.z, wa.w, wb.x, wb.y, wb.z, wb.w};
#pragma unroll
            for (int r = 0; r < 4; ++r)
#pragma unroll
                for (int j = 0; j < 8; ++j)
                    acc[r][j] = fmaf(xr[r], wv[j], acc[r][j]);
        }
        __syncthreads();
    }
    // epilogue: add bias, store
#pragma unroll
    for (int r = 0; r < 4; ++r) {
        int gr = row0 + r0 + r;
        if (gr >= NUM_ENT) continue;
        float4 o0, o1;
        o0.x = acc[r][0] + bias[j0 + 0]; o0.y = acc[r][1] + bias[j0 + 1];
        o0.z = acc[r][2] + bias[j0 + 2]; o0.w = acc[r][3] + bias[j0 + 3];
        o1.x = acc[r][4] + bias[j0 + 4]; o1.y = acc[r][5] + bias[j0 + 5];
        o1.z = acc[r][6] + bias[j0 + 6]; o1.w = acc[r][7] + bias[j0 + 7];
        float4* Y4 = (float4*)Y;
        Y4[gr * 32 + (j0 >> 2)]     = o0;
        Y4[gr * 32 + (j0 >> 2) + 1] = o1;
    }
}

// ---------------------------------------------------------------------------
// Kernel 2: in-place lorentz transform per row. One wave (64 lanes) per row,
// 2 elements per lane.
__global__ __launch_bounds__(256) void k_lorentz(float* __restrict__ Y,
                                                 const float* __restrict__ scale_p) {
    int gid = blockIdx.x * 256 + threadIdx.x;
    int w = gid >> 6, lane = gid & 63;
    if (w >= NUM_ENT) return;
    float es = expf(scale_p[0]);
    float a = Y[w * 128 + lane];
    float b = Y[w * 128 + 64 + lane];
    float y0 = __shfl(a, 0, 64);
    float sq = a * a + b * b;
#pragma unroll
    for (int off = 32; off > 0; off >>= 1) sq += __shfl_xor(sq, off, 64);
    sq -= y0 * y0;                                  // exclude time component
    float time = es / (1.f + expf(-y0)) + 1.1f;     // sigmoid(y0)*exp(scale)+1.1
    float s = sqrtf((time * time - 1.f) / fmaxf(sq, 1e-8f));
    Y[w * 128 + lane]      = (lane == 0) ? time : a * s;
    Y[w * 128 + 64 + lane] = b * s;
}

// ---------------------------------------------------------------------------
// Kernel 3: Xe[edges[i]] += Xl[vertex[i]] - emb_ty[ty[i]]   (atomic scatter)
// 32 lanes per nnz entry, float4 per lane.
__global__ __launch_bounds__(256) void k_scatter1(const float* __restrict__ Xl,
                                                  const float* __restrict__ Ty,
                                                  const int* __restrict__ vertex,
                                                  const int* __restrict__ edges,
                                                  const int* __restrict__ tyi,
                                                  float* __restrict__ Xe) {
    int tid = blockIdx.x * 256 + threadIdx.x;
    int g = tid >> 5, l = tid & 31;
    if (g >= NNZ) return;
    int v = vertex[g], e = edges[g], tt = tyi[g];
    float4 a = ((const float4*)Xl)[v * 32 + l];
    float4 c = ((const float4*)Ty)[tt * 32 + l];
    float* dst = Xe + e * 128 + l * 4;
    atomicAdd(dst + 0, a.x - c.x);
    atomicAdd(dst + 1, a.y - c.y);
    atomicAdd(dst + 2, a.z - c.z);
    atomicAdd(dst + 3, a.w - c.w);
}

// Kernel 4: Xv[vertex[i]] += Xe[edges[i]]
__global__ __launch_bounds__(256) void k_scatter2(const float* __restrict__ Xe,
                                                  const int* __restrict__ vertex,
                                                  const int* __restrict__ edges,
                                                  float* __restrict__ Xv) {
    int tid = blockIdx.x * 256 + threadIdx.x;
    int g = tid >> 5, l = tid & 31;
    if (g >= NNZ) return;
    int v = vertex[g], e = edges[g];
    float4 a = ((const float4*)Xe)[e * 32 + l];
    float* dst = Xv + v * 128 + l * 4;
    atomicAdd(dst + 0, a.x);
    atomicAdd(dst + 1, a.y);
    atomicAdd(dst + 2, a.z);
    atomicAdd(dst + 3, a.w);
}

// ---------------------------------------------------------------------------
// Kernel 5: E_e = logmap0(eps*Xv + Xl), row 0 := 1.0. In-place over Xl buffer.
__global__ __launch_bounds__(256) void k_final(float* __restrict__ XlEe,
                                               const float* __restrict__ Xv,
                                               const float* __restrict__ eps_p) {
    int gid = blockIdx.x * 256 + threadIdx.x;
    int w = gid >> 6, lane = gid & 63;
    if (w >= NUM_ENT) return;
    float eps = eps_p[0];
    float xa = fmaf(eps, Xv[w * 128 + lane],      XlEe[w * 128 + lane]);
    float xb = fmaf(eps, Xv[w * 128 + 64 + lane], XlEe[w * 128 + 64 + lane]);
    float x0 = __shfl(xa, 0, 64);
    float sq = xa * xa + xb * xb;
#pragma unroll
    for (int off = 32; off > 0; off >>= 1) sq += __shfl_xor(sq, off, 64);
    sq = fmaxf(sq - x0 * x0, 0.f);                   // spatial sqnorm
    float ynorm = fmaxf(sqrtf(sq), 1e-8f);           // clip(norm, 1e-8)
    float theta = fmaxf(x0, 1.f + 1e-7f);
    float fac = logf(theta + sqrtf(theta * theta - 1.f)) / ynorm;  // arccosh/norm
    float oa = (lane == 0) ? 0.f : xa * fac;
    float ob = xb * fac;
    if (w == 0) { oa = 1.f; ob = 1.f; }              // E_e.at[0].set(1.0)
    XlEe[w * 128 + lane]      = oa;
    XlEe[w * 128 + 64 + lane] = ob;
}

// ---------------------------------------------------------------------------
// Kernel 6: out[b] = sum_j prod(E_e[e1..e6][j]) * R_e[r_idx][j]. Wave per b.
__global__ __launch_bounds__(256) void k_out(const float* __restrict__ Ee,
                                             const float* __restrict__ R,
                                             const int* __restrict__ r_idx,
                                             const int* __restrict__ e1,
                                             const int* __restrict__ e2,
                                             const int* __restrict__ e3,
                                             const int* __restrict__ e4,
                                             const int* __restrict__ e5,
                                             const int* __restrict__ e6,
                                             float* __restrict__ out) {
    int gid = blockIdx.x * 256 + threadIdx.x;
    int b = gid >> 6, lane = gid & 63;
    if (b >= BATCH) return;
    int i1 = e1[b], i2 = e2[b], i3 = e3[b], i4 = e4[b], i5 = e5[b], i6 = e6[b];
    int rr = r_idx[b];
    float pa = Ee[i1 * 128 + lane] * Ee[i2 * 128 + lane] * Ee[i3 * 128 + lane]
             * Ee[i4 * 128 + lane] * Ee[i5 * 128 + lane] * Ee[i6 * 128 + lane];
    float pb = Ee[i1 * 128 + 64 + lane] * Ee[i2 * 128 + 64 + lane] * Ee[i3 * 128 + 64 + lane]
             * Ee[i4 * 128 + 64 + lane] * Ee[i5 * 128 + 64 + lane] * Ee[i6 * 128 + 64 + lane];
    float ra = (rr == 0) ? 1.f : R[rr * 128 + lane];        // R_e.at[0].set(1.0)
    float rb = (rr == 0) ? 1.f : R[rr * 128 + 64 + lane];
    float s = pa * ra + pb * rb;
#pragma unroll
    for (int off = 32; off > 0; off >>= 1) s += __shfl_xor(s, off, 64);
    if (lane == 0) out[b] = s;
}

// ---------------------------------------------------------------------------
extern "C" void kernel_launch(void* const* d_in, const int* in_sizes, int n_in,
                              void* d_out, int out_size, void* d_ws, size_t ws_size,
                              hipStream_t stream) {
    const float* emb_E     = (const float*)d_in[0];
    const float* emb_R     = (const float*)d_in[1];
    const float* emb_ty    = (const float*)d_in[2];
    const float* lin_W     = (const float*)d_in[3];
    const float* lin_b     = (const float*)d_in[4];
    const float* lin_scale = (const float*)d_in[5];
    const float* eps       = (const float*)d_in[6];
    // d_in[7] = ms (unused by reference)
    const int* r_idx  = (const int*)d_in[8];
    const int* e1     = (const int*)d_in[9];
    const int* e2     = (const int*)d_in[10];
    const int* e3     = (const int*)d_in[11];
    const int* e4     = (const int*)d_in[12];
    const int* e5     = (const int*)d_in[13];
    const int* e6     = (const int*)d_in[14];
    const int* vertex = (const int*)d_in[15];
    const int* edges  = (const int*)d_in[16];
    const int* tyi    = (const int*)d_in[17];
    // d_in[18] = bs (constant)

    float* ws = (float*)d_ws;
    float* Xl = ws + XL_OFF;   // 100000 x 128, becomes E_e in-place
    float* Xe = ws + XE_OFF;   // 200000 x 128
    float* Xv = ws + XV_OFF;   // 100000 x 128

    // zero the two accumulator regions (ws is re-poisoned before every launch)
    hipMemsetAsync(Xe, 0, (size_t)(NUM_EDGES + NUM_ENT) * DIM * sizeof(float), stream);

    k_gemm<<<(NUM_ENT + 63) / 64, 256, 0, stream>>>(emb_E, lin_W, lin_b, Xl);
    k_lorentz<<<(NUM_ENT * 64) / 256, 256, 0, stream>>>(Xl, lin_scale);
    k_scatter1<<<(NNZ * 32) / 256, 256, 0, stream>>>(Xl, emb_ty, vertex, edges, tyi, Xe);
    k_scatter2<<<(NNZ * 32) / 256, 256, 0, stream>>>(Xe, vertex, edges, Xv);
    k_final<<<(NUM_ENT * 64) / 256, 256, 0, stream>>>(Xl, Xv, eps);
    k_out<<<(BATCH * 64) / 256, 256, 0, stream>>>(Xl, emb_R, r_idx,
                                                  e1, e2, e3, e4, e5, e6,
                                                  (float*)d_out);
}

// Round 2
// 765.794 us; speedup vs baseline: 4.6961x; 4.6961x over previous
//
#include <hip/hip_runtime.h>
#include <math.h>

#define NUM_ENT   100000
#define NUM_REL   50
#define NUM_EDGES 200000
#define NNZ       1000000
#define DIM       128
#define BATCH     4096

// ws layout (floats): Xl | Xe | int-region
#define XL_OFF  0
#define XE_OFF  (NUM_ENT * DIM)                     // 12.8M floats
#define INT_OFF (XE_OFF + NUM_EDGES * DIM)          // 38.4M floats
// int region layout (ints, relative to ib):
//   cnt_e[200000] cnt_v[100000]           <- zeroed via one memset
//   start_e[200000] cur_e[200000]
//   start_v[100000] cur_v[100000]
//   bsum_e[256] bsum_v[256]
//   perm_e[1000000] perm_v[1000000]
#define CNT_E   0
#define CNT_V   (CNT_E + NUM_EDGES)
#define START_E (CNT_V + NUM_ENT)
#define CUR_E   (START_E + NUM_EDGES)
#define START_V (CUR_E + NUM_EDGES)
#define CUR_V   (START_V + NUM_ENT)
#define BSUM_E  (CUR_V + NUM_ENT)
#define BSUM_V  (BSUM_E + 256)
#define PERM_E  (BSUM_V + 256)
#define PERM_V  (PERM_E + NNZ)

// ---------------------------------------------------------------------------
// GEMM: Y = X @ W^T + b. Block 256, tile 64 rows x 128 cols, K in 2x64 chunks.
__global__ __launch_bounds__(256) void k_gemm(const float* __restrict__ X,
                                              const float* __restrict__ W,
                                              const float* __restrict__ bias,
                                              float* __restrict__ Y) {
    __shared__ float Xs[64][68];
    __shared__ float Ws[64][132];
    const int t = threadIdx.x;
    const int row0 = blockIdx.x * 64;
    const float4* X4 = (const float4*)X;
    const float4* W4 = (const float4*)W;
    const int tx = t & 15, ty = t >> 4;
    const int j0 = tx * 8;
    const int r0 = ty * 4;

    float acc[4][8];
#pragma unroll
    for (int r = 0; r < 4; ++r)
#pragma unroll
        for (int j = 0; j < 8; ++j) acc[r][j] = 0.f;

    for (int kk = 0; kk < 128; kk += 64) {
#pragma unroll
        for (int i = 0; i < 4; ++i) {
            int q = t + 256 * i;
            int r = q >> 4, k4 = q & 15;
            int gr = row0 + r;
            float4 v = make_float4(0.f, 0.f, 0.f, 0.f);
            if (gr < NUM_ENT) v = X4[gr * 32 + (kk >> 2) + k4];
            Xs[k4 * 4 + 0][r] = v.x; Xs[k4 * 4 + 1][r] = v.y;
            Xs[k4 * 4 + 2][r] = v.z; Xs[k4 * 4 + 3][r] = v.w;
        }
#pragma unroll
        for (int i = 0; i < 8; ++i) {
            int q = t + 256 * i;
            int j = q >> 4, k4 = q & 15;
            float4 v = W4[j * 32 + (kk >> 2) + k4];
            Ws[k4 * 4 + 0][j] = v.x; Ws[k4 * 4 + 1][j] = v.y;
            Ws[k4 * 4 + 2][j] = v.z; Ws[k4 * 4 + 3][j] = v.w;
        }
        __syncthreads();
#pragma unroll 8
        for (int k = 0; k < 64; ++k) {
            float4 xv = *(const float4*)&Xs[k][r0];
            float4 wa = *(const float4*)&Ws[k][j0];
            float4 wb = *(const float4*)&Ws[k][j0 + 4];
            float xr[4] = {xv.x, xv.y, xv.z, xv.w};
            float wv[8] = {wa.x, wa.y, wa.z, wa.w, wb.x, wb.y, wb.z, wb.w};
#pragma unroll
            for (int r = 0; r < 4; ++r)
#pragma unroll
                for (int j = 0; j < 8; ++j)
                    acc[r][j] = fmaf(xr[r], wv[j], acc[r][j]);
        }
        __syncthreads();
    }
#pragma unroll
    for (int r = 0; r < 4; ++r) {
        int gr = row0 + r0 + r;
        if (gr >= NUM_ENT) continue;
        float4 o0, o1;
        o0.x = acc[r][0] + bias[j0 + 0]; o0.y = acc[r][1] + bias[j0 + 1];
        o0.z = acc[r][2] + bias[j0 + 2]; o0.w = acc[r][3] + bias[j0 + 3];
        o1.x = acc[r][4] + bias[j0 + 4]; o1.y = acc[r][5] + bias[j0 + 5];
        o1.z = acc[r][6] + bias[j0 + 6]; o1.w = acc[r][7] + bias[j0 + 7];
        float4* Y4 = (float4*)Y;
        Y4[gr * 32 + (j0 >> 2)]     = o0;
        Y4[gr * 32 + (j0 >> 2) + 1] = o1;
    }
}

// ---------------------------------------------------------------------------
// Lorentz transform, in place. One wave per row, 2 floats/lane.
__global__ __launch_bounds__(256) void k_lorentz(float* __restrict__ Y,
                                                 const float* __restrict__ scale_p) {
    int gid = blockIdx.x * 256 + threadIdx.x;
    int w = gid >> 6, lane = gid & 63;
    if (w >= NUM_ENT) return;
    float es = expf(scale_p[0]);
    float a = Y[w * 128 + lane];
    float b = Y[w * 128 + 64 + lane];
    float y0 = __shfl(a, 0, 64);
    float sq = a * a + b * b;
#pragma unroll
    for (int off = 32; off > 0; off >>= 1) sq += __shfl_xor(sq, off, 64);
    sq -= y0 * y0;
    float time = es / (1.f + expf(-y0)) + 1.1f;
    float s = sqrtf((time * time - 1.f) / fmaxf(sq, 1e-8f));
    Y[w * 128 + lane]      = (lane == 0) ? time : a * s;
    Y[w * 128 + 64 + lane] = b * s;
}

// ---------------------------------------------------------------------------
// CSR build: histogram both index arrays.
__global__ __launch_bounds__(256) void k_hist(const int* __restrict__ edges,
                                              const int* __restrict__ vertex,
                                              int* __restrict__ cnt_e,
                                              int* __restrict__ cnt_v) {
    int i = blockIdx.x * 256 + threadIdx.x;
    if (i >= NNZ) return;
    atomicAdd(&cnt_e[edges[i]], 1);
    atomicAdd(&cnt_v[vertex[i]], 1);
}

// Block-level exclusive scan: 1024 elems/block (256 thr x 4).
__global__ __launch_bounds__(256) void k_scan_block(const int* __restrict__ cnt,
                                                    int* __restrict__ out,
                                                    int* __restrict__ bsum, int N) {
    __shared__ int lds[256];
    int t = threadIdx.x;
    int base = blockIdx.x * 1024 + t * 4;
    int a[4];
#pragma unroll
    for (int j = 0; j < 4; ++j) a[j] = (base + j < N) ? cnt[base + j] : 0;
    int local = a[0] + a[1] + a[2] + a[3];
    lds[t] = local;
    __syncthreads();
    for (int off = 1; off < 256; off <<= 1) {
        int add = (t >= off) ? lds[t - off] : 0;
        __syncthreads();
        if (t >= off) lds[t] += add;
        __syncthreads();
    }
    int excl = lds[t] - local;
    if (t == 255) bsum[blockIdx.x] = lds[255];
    int s = excl;
#pragma unroll
    for (int j = 0; j < 4; ++j) {
        if (base + j < N) out[base + j] = s;
        s += a[j];
    }
}

// Single-block exclusive scan over <=256 block sums, in place.
__global__ __launch_bounds__(256) void k_scan_top(int* __restrict__ bs, int nb) {
    __shared__ int lds[256];
    int t = threadIdx.x;
    int v = (t < nb) ? bs[t] : 0;
    lds[t] = v;
    __syncthreads();
    for (int off = 1; off < 256; off <<= 1) {
        int add = (t >= off) ? lds[t - off] : 0;
        __syncthreads();
        if (t >= off) lds[t] += add;
        __syncthreads();
    }
    if (t < nb) bs[t] = lds[t] - v;
}

// Add block offsets; also produce cursor copy.
__global__ __launch_bounds__(256) void k_scan_add(int* __restrict__ out,
                                                  int* __restrict__ cur,
                                                  const int* __restrict__ bsum, int N) {
    int i = blockIdx.x * 256 + threadIdx.x;
    if (i >= N) return;
    int v = out[i] + bsum[i >> 10];
    out[i] = v;
    cur[i] = v;
}

// Fill both permutations.
__global__ __launch_bounds__(256) void k_fill(const int* __restrict__ edges,
                                              const int* __restrict__ vertex,
                                              int* __restrict__ cur_e,
                                              int* __restrict__ cur_v,
                                              int* __restrict__ perm_e,
                                              int* __restrict__ perm_v) {
    int i = blockIdx.x * 256 + threadIdx.x;
    if (i >= NNZ) return;
    int p = atomicAdd(&cur_e[edges[i]], 1);
    perm_e[p] = i;
    int q = atomicAdd(&cur_v[vertex[i]], 1);
    perm_v[q] = i;
}

// ---------------------------------------------------------------------------
// Xe[e] = sum over contributors (Xl[vertex[i]] - Ty[ty[i]]). 32 lanes/edge.
__global__ __launch_bounds__(256) void k_gatherE(const float* __restrict__ Xl,
                                                 const float* __restrict__ Ty,
                                                 const int* __restrict__ vertex,
                                                 const int* __restrict__ tyi,
                                                 const int* __restrict__ start_e,
                                                 const int* __restrict__ cnt_e,
                                                 const int* __restrict__ perm_e,
                                                 float* __restrict__ Xe) {
    int tid = blockIdx.x * 256 + threadIdx.x;
    int e = tid >> 5, l = tid & 31;
    if (e >= NUM_EDGES) return;
    int s = start_e[e], n = cnt_e[e];
    const float4* Xl4 = (const float4*)Xl;
    const float4* Ty4 = (const float4*)Ty;
    float4 acc = make_float4(0.f, 0.f, 0.f, 0.f);
    for (int k = 0; k < n; ++k) {
        int i = perm_e[s + k];
        int v = vertex[i], tt = tyi[i];
        float4 a = Xl4[v * 32 + l];
        float4 c = Ty4[tt * 32 + l];
        acc.x += a.x - c.x; acc.y += a.y - c.y;
        acc.z += a.z - c.z; acc.w += a.w - c.w;
    }
    ((float4*)Xe)[e * 32 + l] = acc;
}

// ---------------------------------------------------------------------------
// Fused: Xv gather + E_e = logmap0(eps*Xv + Xl) + row-0 fixup, in place in Xl.
// One wave per vertex, 2 floats/lane.
__global__ __launch_bounds__(256) void k_gatherV_final(float* __restrict__ XlEe,
                                                       const float* __restrict__ Xe,
                                                       const int* __restrict__ edges,
                                                       const int* __restrict__ start_v,
                                                       const int* __restrict__ cnt_v,
                                                       const int* __restrict__ perm_v,
                                                       const float* __restrict__ eps_p) {
    int gid = blockIdx.x * 256 + threadIdx.x;
    int w = gid >> 6, lane = gid & 63;
    if (w >= NUM_ENT) return;
    int s = start_v[w], n = cnt_v[w];
    float sa = 0.f, sb = 0.f;
    for (int k = 0; k < n; ++k) {
        int i = perm_v[s + k];
        int e = edges[i];
        sa += Xe[e * 128 + lane];
        sb += Xe[e * 128 + 64 + lane];
    }
    float eps = eps_p[0];
    float xa = fmaf(eps, sa, XlEe[w * 128 + lane]);
    float xb = fmaf(eps, sb, XlEe[w * 128 + 64 + lane]);
    float x0 = __shfl(xa, 0, 64);
    float sq = xa * xa + xb * xb;
#pragma unroll
    for (int off = 32; off > 0; off >>= 1) sq += __shfl_xor(sq, off, 64);
    sq = fmaxf(sq - x0 * x0, 0.f);
    float ynorm = fmaxf(sqrtf(sq), 1e-8f);
    float theta = fmaxf(x0, 1.f + 1e-7f);
    float fac = logf(theta + sqrtf(theta * theta - 1.f)) / ynorm;  // arccosh
    float oa = (lane == 0) ? 0.f : xa * fac;
    float ob = xb * fac;
    if (w == 0) { oa = 1.f; ob = 1.f; }
    XlEe[w * 128 + lane]      = oa;
    XlEe[w * 128 + 64 + lane] = ob;
}

// ---------------------------------------------------------------------------
// out[b] = sum_j prod(E_e[e1..e6][j]) * R_e[r_idx][j]. Wave per b.
__global__ __launch_bounds__(256) void k_out(const float* __restrict__ Ee,
                                             const float* __restrict__ R,
                                             const int* __restrict__ r_idx,
                                             const int* __restrict__ e1,
                                             const int* __restrict__ e2,
                                             const int* __restrict__ e3,
                                             const int* __restrict__ e4,
                                             const int* __restrict__ e5,
                                             const int* __restrict__ e6,
                                             float* __restrict__ out) {
    int gid = blockIdx.x * 256 + threadIdx.x;
    int b = gid >> 6, lane = gid & 63;
    if (b >= BATCH) return;
    int i1 = e1[b], i2 = e2[b], i3 = e3[b], i4 = e4[b], i5 = e5[b], i6 = e6[b];
    int rr = r_idx[b];
    float pa = Ee[i1 * 128 + lane] * Ee[i2 * 128 + lane] * Ee[i3 * 128 + lane]
             * Ee[i4 * 128 + lane] * Ee[i5 * 128 + lane] * Ee[i6 * 128 + lane];
    float pb = Ee[i1 * 128 + 64 + lane] * Ee[i2 * 128 + 64 + lane] * Ee[i3 * 128 + 64 + lane]
             * Ee[i4 * 128 + 64 + lane] * Ee[i5 * 128 + 64 + lane] * Ee[i6 * 128 + 64 + lane];
    float ra = (rr == 0) ? 1.f : R[rr * 128 + lane];
    float rb = (rr == 0) ? 1.f : R[rr * 128 + 64 + lane];
    float s = pa * ra + pb * rb;
#pragma unroll
    for (int off = 32; off > 0; off >>= 1) s += __shfl_xor(s, off, 64);
    if (lane == 0) out[b] = s;
}

// ---------------------------------------------------------------------------
extern "C" void kernel_launch(void* const* d_in, const int* in_sizes, int n_in,
                              void* d_out, int out_size, void* d_ws, size_t ws_size,
                              hipStream_t stream) {
    const float* emb_E     = (const float*)d_in[0];
    const float* emb_R     = (const float*)d_in[1];
    const float* emb_ty    = (const float*)d_in[2];
    const float* lin_W     = (const float*)d_in[3];
    const float* lin_b     = (const float*)d_in[4];
    const float* lin_scale = (const float*)d_in[5];
    const float* eps       = (const float*)d_in[6];
    const int* r_idx  = (const int*)d_in[8];
    const int* e1     = (const int*)d_in[9];
    const int* e2     = (const int*)d_in[10];
    const int* e3     = (const int*)d_in[11];
    const int* e4     = (const int*)d_in[12];
    const int* e5     = (const int*)d_in[13];
    const int* e6     = (const int*)d_in[14];
    const int* vertex = (const int*)d_in[15];
    const int* edges  = (const int*)d_in[16];
    const int* tyi    = (const int*)d_in[17];

    float* ws = (float*)d_ws;
    float* Xl = ws + XL_OFF;   // 100000 x 128, becomes E_e in place
    float* Xe = ws + XE_OFF;   // 200000 x 128
    int*   ib = (int*)(ws + INT_OFF);
    int* cnt_e   = ib + CNT_E;
    int* cnt_v   = ib + CNT_V;
    int* start_e = ib + START_E;
    int* cur_e   = ib + CUR_E;
    int* start_v = ib + START_V;
    int* cur_v   = ib + CUR_V;
    int* bsum_e  = ib + BSUM_E;
    int* bsum_v  = ib + BSUM_V;
    int* perm_e  = ib + PERM_E;
    int* perm_v  = ib + PERM_V;

    // zero the two histograms (contiguous: cnt_e then cnt_v)
    hipMemsetAsync(cnt_e, 0, (size_t)(NUM_EDGES + NUM_ENT) * sizeof(int), stream);

    const int NBE = (NUM_EDGES + 1023) / 1024;   // 196
    const int NBV = (NUM_ENT  + 1023) / 1024;    // 98

    // CSR build (overlaps conceptually with gemm on the same stream order)
    k_hist<<<(NNZ + 255) / 256, 256, 0, stream>>>(edges, vertex, cnt_e, cnt_v);
    k_scan_block<<<NBE, 256, 0, stream>>>(cnt_e, start_e, bsum_e, NUM_EDGES);
    k_scan_block<<<NBV, 256, 0, stream>>>(cnt_v, start_v, bsum_v, NUM_ENT);
    k_scan_top<<<1, 256, 0, stream>>>(bsum_e, NBE);
    k_scan_top<<<1, 256, 0, stream>>>(bsum_v, NBV);
    k_scan_add<<<(NUM_EDGES + 255) / 256, 256, 0, stream>>>(start_e, cur_e, bsum_e, NUM_EDGES);
    k_scan_add<<<(NUM_ENT + 255) / 256, 256, 0, stream>>>(start_v, cur_v, bsum_v, NUM_ENT);
    k_fill<<<(NNZ + 255) / 256, 256, 0, stream>>>(edges, vertex, cur_e, cur_v, perm_e, perm_v);

    // dense pipeline
    k_gemm<<<(NUM_ENT + 63) / 64, 256, 0, stream>>>(emb_E, lin_W, lin_b, Xl);
    k_lorentz<<<(NUM_ENT * 64) / 256, 256, 0, stream>>>(Xl, lin_scale);
    k_gatherE<<<(NUM_EDGES * 32) / 256, 256, 0, stream>>>(Xl, emb_ty, vertex, tyi,
                                                          start_e, cnt_e, perm_e, Xe);
    k_gatherV_final<<<(NUM_ENT * 64) / 256, 256, 0, stream>>>(Xl, Xe, edges,
                                                              start_v, cnt_v, perm_v, eps);
    k_out<<<(BATCH * 64) / 256, 256, 0, stream>>>(Xl, emb_R, r_idx,
                                                  e1, e2, e3, e4, e5, e6,
                                                  (float*)d_out);
}

// Round 3
// 480.793 us; speedup vs baseline: 7.4798x; 1.5928x over previous
//
#include <hip/hip_runtime.h>
#include <math.h>

#define NUM_ENT   100000
#define NUM_REL   50
#define NUM_EDGES 200000
#define NNZ       1000000
#define DIM       128
#define BATCH     4096

// ws layout (floats): Xl | Xe | int-region
#define XL_OFF  0
#define XE_OFF  (NUM_ENT * DIM)                     // 12.8M floats
#define INT_OFF (XE_OFF + NUM_EDGES * DIM)          // 38.4M floats
// int region (ints, relative to ib):
//  [zeroed by one memset:] cnt_e[200000] cnt_v[100000] flag_v[100000] flag_e[200000] nv[1]
//  start_e[200000] cur_e[200000] start_v[100000] cur_v[100000]
//  bsum_e[256] bsum_v[256]
//  pay_e[1000000] pay_v[1000000] vlist[24640]
#define CNT_E   0
#define CNT_V   (CNT_E + NUM_EDGES)
#define FLAG_V  (CNT_V + NUM_ENT)
#define FLAG_E  (FLAG_V + NUM_ENT)
#define NV_CNT  (FLAG_E + NUM_EDGES)
#define ZERO_N  (NV_CNT + 1)                        // memset span
#define START_E (ZERO_N)
#define CUR_E   (START_E + NUM_EDGES)
#define START_V (CUR_E + NUM_EDGES)
#define CUR_V   (START_V + NUM_ENT)
#define BSUM_E  (CUR_V + NUM_ENT)
#define BSUM_V  (BSUM_E + 256)
#define PAY_E   (BSUM_V + 256)
#define PAY_V   (PAY_E + NNZ)
#define VLIST   (PAY_V + NNZ)

// ---------------------------------------------------------------------------
// GEMM fused with lorentz: Y = lorentz(X @ W^T + b). Block 256, tile 64x128.
// Each block holds 64 complete rows -> per-row reduction in LDS for the
// lorentz rescale (saves a full 102 MB Xl round-trip vs separate kernel).
__global__ __launch_bounds__(256) void k_gemm_lorentz(const float* __restrict__ X,
                                                      const float* __restrict__ W,
                                                      const float* __restrict__ bias,
                                                      const float* __restrict__ scale_p,
                                                      float* __restrict__ Y) {
    __shared__ float Xs[64][68];
    __shared__ float Ws[64][132];
    __shared__ float Ps[64][17];   // per-(row,tx) spatial sq partials
    __shared__ float Y0s[64];      // col-0 per row
    __shared__ float Ss[64];       // scale per row
    __shared__ float Ts[64];       // time per row
    const int t = threadIdx.x;
    const int row0 = blockIdx.x * 64;
    const float4* X4 = (const float4*)X;
    const float4* W4 = (const float4*)W;
    const int tx = t & 15, ty = t >> 4;
    const int j0 = tx * 8;
    const int r0 = ty * 4;

    float acc[4][8];
#pragma unroll
    for (int r = 0; r < 4; ++r)
#pragma unroll
        for (int j = 0; j < 8; ++j) acc[r][j] = 0.f;

    for (int kk = 0; kk < 128; kk += 64) {
#pragma unroll
        for (int i = 0; i < 4; ++i) {
            int q = t + 256 * i;
            int r = q >> 4, k4 = q & 15;
            int gr = row0 + r;
            float4 v = make_float4(0.f, 0.f, 0.f, 0.f);
            if (gr < NUM_ENT) v = X4[gr * 32 + (kk >> 2) + k4];
            Xs[k4 * 4 + 0][r] = v.x; Xs[k4 * 4 + 1][r] = v.y;
            Xs[k4 * 4 + 2][r] = v.z; Xs[k4 * 4 + 3][r] = v.w;
        }
#pragma unroll
        for (int i = 0; i < 8; ++i) {
            int q = t + 256 * i;
            int j = q >> 4, k4 = q & 15;
            float4 v = W4[j * 32 + (kk >> 2) + k4];
            Ws[k4 * 4 + 0][j] = v.x; Ws[k4 * 4 + 1][j] = v.y;
            Ws[k4 * 4 + 2][j] = v.z; Ws[k4 * 4 + 3][j] = v.w;
        }
        __syncthreads();
#pragma unroll 8
        for (int k = 0; k < 64; ++k) {
            float4 xv = *(const float4*)&Xs[k][r0];
            float4 wa = *(const float4*)&Ws[k][j0];
            float4 wb = *(const float4*)&Ws[k][j0 + 4];
            float xr[4] = {xv.x, xv.y, xv.z, xv.w};
            float wv[8] = {wa.x, wa.y, wa.z, wa.w, wb.x, wb.y, wb.z, wb.w};
#pragma unroll
            for (int r = 0; r < 4; ++r)
#pragma unroll
                for (int j = 0; j < 8; ++j)
                    acc[r][j] = fmaf(xr[r], wv[j], acc[r][j]);
        }
        __syncthreads();
    }
    // bias + per-row spatial-sqnorm partials
#pragma unroll
    for (int r = 0; r < 4; ++r) {
        float p = 0.f;
#pragma unroll
        for (int j = 0; j < 8; ++j) {
            float yv = acc[r][j] + bias[j0 + j];
            acc[r][j] = yv;
            if (j0 + j != 0) p += yv * yv;   // exclude time col
        }
        Ps[r0 + r][tx] = p;
        if (tx == 0) Y0s[r0 + r] = acc[r][0];
    }
    __syncthreads();
    if (t < 64) {
        float sq = 0.f;
#pragma unroll
        for (int jj = 0; jj < 16; ++jj) sq += Ps[t][jj];
        float es = expf(scale_p[0]);
        float y0 = Y0s[t];
        float time = es / (1.f + expf(-y0)) + 1.1f;
        Ss[t] = sqrtf((time * time - 1.f) / fmaxf(sq, 1e-8f));
        Ts[t] = time;
    }
    __syncthreads();
#pragma unroll
    for (int r = 0; r < 4; ++r) {
        int gr = row0 + r0 + r;
        if (gr >= NUM_ENT) continue;
        float s = Ss[r0 + r];
        float4 o0, o1;
        o0.x = (tx == 0) ? Ts[r0 + r] : acc[r][0] * s;
        o0.y = acc[r][1] * s; o0.z = acc[r][2] * s; o0.w = acc[r][3] * s;
        o1.x = acc[r][4] * s; o1.y = acc[r][5] * s;
        o1.z = acc[r][6] * s; o1.w = acc[r][7] * s;
        float4* Y4 = (float4*)Y;
        Y4[gr * 32 + (j0 >> 2)]     = o0;
        Y4[gr * 32 + (j0 >> 2) + 1] = o1;
    }
}

// ---------------------------------------------------------------------------
// Flag + dedup + compact the entities actually read by the output stage.
__global__ __launch_bounds__(256) void k_flagv(const int* __restrict__ e1,
                                               const int* __restrict__ e2,
                                               const int* __restrict__ e3,
                                               const int* __restrict__ e4,
                                               const int* __restrict__ e5,
                                               const int* __restrict__ e6,
                                               int* __restrict__ flag_v,
                                               int* __restrict__ vlist,
                                               int* __restrict__ nv) {
    int i = blockIdx.x * 256 + threadIdx.x;
    if (i >= BATCH) return;
    int idx[6] = {e1[i], e2[i], e3[i], e4[i], e5[i], e6[i]};
#pragma unroll
    for (int k = 0; k < 6; ++k) {
        int v = idx[k];
        if (atomicExch(&flag_v[v], 1) == 0)
            vlist[atomicAdd(nv, 1)] = v;
    }
}

// Histogram. cnt_e: all contributors. cnt_v + flag_e: only for flagged verts.
__global__ __launch_bounds__(256) void k_hist(const int* __restrict__ edges,
                                              const int* __restrict__ vertex,
                                              const int* __restrict__ flag_v,
                                              int* __restrict__ cnt_e,
                                              int* __restrict__ cnt_v,
                                              int* __restrict__ flag_e) {
    int i = blockIdx.x * 256 + threadIdx.x;
    if (i >= NNZ) return;
    int v = vertex[i], e = edges[i];
    atomicAdd(&cnt_e[e], 1);
    if (flag_v[v]) {
        atomicAdd(&cnt_v[v], 1);
        flag_e[e] = 1;               // racy store of 1: fine
    }
}

// Block-level exclusive scan: 1024 elems/block (256 thr x 4).
__global__ __launch_bounds__(256) void k_scan_block(const int* __restrict__ cnt,
                                                    int* __restrict__ out,
                                                    int* __restrict__ bsum, int N) {
    __shared__ int lds[256];
    int t = threadIdx.x;
    int base = blockIdx.x * 1024 + t * 4;
    int a[4];
#pragma unroll
    for (int j = 0; j < 4; ++j) a[j] = (base + j < N) ? cnt[base + j] : 0;
    int local = a[0] + a[1] + a[2] + a[3];
    lds[t] = local;
    __syncthreads();
    for (int off = 1; off < 256; off <<= 1) {
        int add = (t >= off) ? lds[t - off] : 0;
        __syncthreads();
        if (t >= off) lds[t] += add;
        __syncthreads();
    }
    int excl = lds[t] - local;
    if (t == 255) bsum[blockIdx.x] = lds[255];
    int s = excl;
#pragma unroll
    for (int j = 0; j < 4; ++j) {
        if (base + j < N) out[base + j] = s;
        s += a[j];
    }
}

__global__ __launch_bounds__(256) void k_scan_top(int* __restrict__ bs, int nb) {
    __shared__ int lds[256];
    int t = threadIdx.x;
    int v = (t < nb) ? bs[t] : 0;
    lds[t] = v;
    __syncthreads();
    for (int off = 1; off < 256; off <<= 1) {
        int add = (t >= off) ? lds[t - off] : 0;
        __syncthreads();
        if (t >= off) lds[t] += add;
        __syncthreads();
    }
    if (t < nb) bs[t] = lds[t] - v;
}

__global__ __launch_bounds__(256) void k_scan_add(int* __restrict__ out,
                                                  int* __restrict__ cur,
                                                  const int* __restrict__ bsum, int N) {
    int i = blockIdx.x * 256 + threadIdx.x;
    if (i >= N) return;
    int v = out[i] + bsum[i >> 10];
    out[i] = v;
    cur[i] = v;
}

// Fill payload arrays (gated on demand flags). pay_e packs (vertex<<9)|ty.
__global__ __launch_bounds__(256) void k_fill(const int* __restrict__ edges,
                                              const int* __restrict__ vertex,
                                              const int* __restrict__ tyi,
                                              const int* __restrict__ flag_e,
                                              const int* __restrict__ flag_v,
                                              int* __restrict__ cur_e,
                                              int* __restrict__ cur_v,
                                              int* __restrict__ pay_e,
                                              int* __restrict__ pay_v) {
    int i = blockIdx.x * 256 + threadIdx.x;
    if (i >= NNZ) return;
    int v = vertex[i], e = edges[i], tt = tyi[i];
    if (flag_e[e]) {
        int p = atomicAdd(&cur_e[e], 1);
        pay_e[p] = (v << 9) | tt;
    }
    if (flag_v[v]) {
        int q = atomicAdd(&cur_v[v], 1);
        pay_v[q] = e;
    }
}

// ---------------------------------------------------------------------------
// Xe[e] = sum over contributors (Xl[v] - Ty[tt]), flagged edges only.
// 32 lanes per edge, float4/lane.
__global__ __launch_bounds__(256) void k_gatherE(const float* __restrict__ Xl,
                                                 const float* __restrict__ Ty,
                                                 const int* __restrict__ flag_e,
                                                 const int* __restrict__ start_e,
                                                 const int* __restrict__ cnt_e,
                                                 const int* __restrict__ pay_e,
                                                 float* __restrict__ Xe) {
    int tid = blockIdx.x * 256 + threadIdx.x;
    int e = tid >> 5, l = tid & 31;
    if (e >= NUM_EDGES) return;
    if (!flag_e[e]) return;
    int s = start_e[e], n = cnt_e[e];
    const float4* Xl4 = (const float4*)Xl;
    const float4* Ty4 = (const float4*)Ty;
    float4 acc = make_float4(0.f, 0.f, 0.f, 0.f);
    for (int k = 0; k < n; ++k) {
        int pe = pay_e[s + k];
        int v = pe >> 9, tt = pe & 511;
        float4 a = Xl4[v * 32 + l];
        float4 c = Ty4[tt * 32 + l];
        acc.x += a.x - c.x; acc.y += a.y - c.y;
        acc.z += a.z - c.z; acc.w += a.w - c.w;
    }
    ((float4*)Xe)[e * 32 + l] = acc;
}

// ---------------------------------------------------------------------------
// For flagged vertices only: Xv gather + E_e = logmap0(eps*Xv + Xl) + row-0
// fixup, in place in Xl. One wave per flagged vertex (via vlist).
__global__ __launch_bounds__(256) void k_gatherV_final(float* __restrict__ XlEe,
                                                       const float* __restrict__ Xe,
                                                       const int* __restrict__ start_v,
                                                       const int* __restrict__ cnt_v,
                                                       const int* __restrict__ pay_v,
                                                       const int* __restrict__ vlist,
                                                       const int* __restrict__ nv_p,
                                                       const float* __restrict__ eps_p) {
    int gid = blockIdx.x * 256 + threadIdx.x;
    int idx = gid >> 6, lane = gid & 63;
    if (idx >= nv_p[0]) return;
    int w = vlist[idx];
    int s = start_v[w], n = cnt_v[w];
    float sa = 0.f, sb = 0.f;
    for (int k = 0; k < n; ++k) {
        int e = pay_v[s + k];
        sa += Xe[e * 128 + lane];
        sb += Xe[e * 128 + 64 + lane];
    }
    float eps = eps_p[0];
    float xa = fmaf(eps, sa, XlEe[w * 128 + lane]);
    float xb = fmaf(eps, sb, XlEe[w * 128 + 64 + lane]);
    float x0 = __shfl(xa, 0, 64);
    float sq = xa * xa + xb * xb;
#pragma unroll
    for (int off = 32; off > 0; off >>= 1) sq += __shfl_xor(sq, off, 64);
    sq = fmaxf(sq - x0 * x0, 0.f);
    float ynorm = fmaxf(sqrtf(sq), 1e-8f);
    float theta = fmaxf(x0, 1.f + 1e-7f);
    float fac = logf(theta + sqrtf(theta * theta - 1.f)) / ynorm;  // arccosh
    float oa = (lane == 0) ? 0.f : xa * fac;
    float ob = xb * fac;
    if (w == 0) { oa = 1.f; ob = 1.f; }
    XlEe[w * 128 + lane]      = oa;
    XlEe[w * 128 + 64 + lane] = ob;
}

// ---------------------------------------------------------------------------
// out[b] = sum_j prod(E_e[e1..e6][j]) * R_e[r_idx][j]. Wave per b.
__global__ __launch_bounds__(256) void k_out(const float* __restrict__ Ee,
                                             const float* __restrict__ R,
                                             const int* __restrict__ r_idx,
                                             const int* __restrict__ e1,
                                             const int* __restrict__ e2,
                                             const int* __restrict__ e3,
                                             const int* __restrict__ e4,
                                             const int* __restrict__ e5,
                                             const int* __restrict__ e6,
                                             float* __restrict__ out) {
    int gid = blockIdx.x * 256 + threadIdx.x;
    int b = gid >> 6, lane = gid & 63;
    if (b >= BATCH) return;
    int i1 = e1[b], i2 = e2[b], i3 = e3[b], i4 = e4[b], i5 = e5[b], i6 = e6[b];
    int rr = r_idx[b];
    float pa = Ee[i1 * 128 + lane] * Ee[i2 * 128 + lane] * Ee[i3 * 128 + lane]
             * Ee[i4 * 128 + lane] * Ee[i5 * 128 + lane] * Ee[i6 * 128 + lane];
    float pb = Ee[i1 * 128 + 64 + lane] * Ee[i2 * 128 + 64 + lane] * Ee[i3 * 128 + 64 + lane]
             * Ee[i4 * 128 + 64 + lane] * Ee[i5 * 128 + 64 + lane] * Ee[i6 * 128 + 64 + lane];
    float ra = (rr == 0) ? 1.f : R[rr * 128 + lane];
    float rb = (rr == 0) ? 1.f : R[rr * 128 + 64 + lane];
    float s = pa * ra + pb * rb;
#pragma unroll
    for (int off = 32; off > 0; off >>= 1) s += __shfl_xor(s, off, 64);
    if (lane == 0) out[b] = s;
}

// ---------------------------------------------------------------------------
extern "C" void kernel_launch(void* const* d_in, const int* in_sizes, int n_in,
                              void* d_out, int out_size, void* d_ws, size_t ws_size,
                              hipStream_t stream) {
    const float* emb_E     = (const float*)d_in[0];
    const float* emb_R     = (const float*)d_in[1];
    const float* emb_ty    = (const float*)d_in[2];
    const float* lin_W     = (const float*)d_in[3];
    const float* lin_b     = (const float*)d_in[4];
    const float* lin_scale = (const float*)d_in[5];
    const float* eps       = (const float*)d_in[6];
    const int* r_idx  = (const int*)d_in[8];
    const int* e1     = (const int*)d_in[9];
    const int* e2     = (const int*)d_in[10];
    const int* e3     = (const int*)d_in[11];
    const int* e4     = (const int*)d_in[12];
    const int* e5     = (const int*)d_in[13];
    const int* e6     = (const int*)d_in[14];
    const int* vertex = (const int*)d_in[15];
    const int* edges  = (const int*)d_in[16];
    const int* tyi    = (const int*)d_in[17];

    float* ws = (float*)d_ws;
    float* Xl = ws + XL_OFF;   // 100000 x 128, becomes E_e in place
    float* Xe = ws + XE_OFF;   // 200000 x 128
    int*   ib = (int*)(ws + INT_OFF);
    int* cnt_e   = ib + CNT_E;
    int* cnt_v   = ib + CNT_V;
    int* flag_v  = ib + FLAG_V;
    int* flag_e  = ib + FLAG_E;
    int* nv      = ib + NV_CNT;
    int* start_e = ib + START_E;
    int* cur_e   = ib + CUR_E;
    int* start_v = ib + START_V;
    int* cur_v   = ib + CUR_V;
    int* bsum_e  = ib + BSUM_E;
    int* bsum_v  = ib + BSUM_V;
    int* pay_e   = ib + PAY_E;
    int* pay_v   = ib + PAY_V;
    int* vlist   = ib + VLIST;

    // zero cnt_e|cnt_v|flag_v|flag_e|nv in one shot
    hipMemsetAsync(cnt_e, 0, (size_t)ZERO_N * sizeof(int), stream);

    const int NBE = (NUM_EDGES + 1023) / 1024;   // 196
    const int NBV = (NUM_ENT  + 1023) / 1024;    // 98

    k_flagv<<<(BATCH + 255) / 256, 256, 0, stream>>>(e1, e2, e3, e4, e5, e6,
                                                     flag_v, vlist, nv);
    k_hist<<<(NNZ + 255) / 256, 256, 0, stream>>>(edges, vertex, flag_v,
                                                  cnt_e, cnt_v, flag_e);
    k_scan_block<<<NBE, 256, 0, stream>>>(cnt_e, start_e, bsum_e, NUM_EDGES);
    k_scan_block<<<NBV, 256, 0, stream>>>(cnt_v, start_v, bsum_v, NUM_ENT);
    k_scan_top<<<1, 256, 0, stream>>>(bsum_e, NBE);
    k_scan_top<<<1, 256, 0, stream>>>(bsum_v, NBV);
    k_scan_add<<<(NUM_EDGES + 255) / 256, 256, 0, stream>>>(start_e, cur_e, bsum_e, NUM_EDGES);
    k_scan_add<<<(NUM_ENT + 255) / 256, 256, 0, stream>>>(start_v, cur_v, bsum_v, NUM_ENT);
    k_fill<<<(NNZ + 255) / 256, 256, 0, stream>>>(edges, vertex, tyi, flag_e, flag_v,
                                                  cur_e, cur_v, pay_e, pay_v);

    k_gemm_lorentz<<<(NUM_ENT + 63) / 64, 256, 0, stream>>>(emb_E, lin_W, lin_b,
                                                            lin_scale, Xl);
    k_gatherE<<<(NUM_EDGES * 32) / 256, 256, 0, stream>>>(Xl, emb_ty, flag_e,
                                                          start_e, cnt_e, pay_e, Xe);
    k_gatherV_final<<<(BATCH * 6 * 64) / 256, 256, 0, stream>>>(Xl, Xe, start_v, cnt_v,
                                                                pay_v, vlist, nv, eps);
    k_out<<<(BATCH * 64) / 256, 256, 0, stream>>>(Xl, emb_R, r_idx,
                                                  e1, e2, e3, e4, e5, e6,
                                                  (float*)d_out);
}

// Round 4
// 439.134 us; speedup vs baseline: 8.1894x; 1.0949x over previous
//
#include <hip/hip_runtime.h>
#include <math.h>

#define NUM_ENT   100000
#define NUM_REL   50
#define NUM_EDGES 200000
#define NNZ       1000000
#define DIM       128
#define BATCH     4096

// ws layout (floats): Xl | Xe | int-region
#define XL_OFF  0
#define XE_OFF  (NUM_ENT * DIM)                     // 12.8M floats
#define INT_OFF (XE_OFF + NUM_EDGES * DIM)          // 38.4M floats
// int region (ints, relative to ib):
//  [zeroed by one memset:] cnt_e[200000] cnt_v[100000] flag_v[100000] flag_e[200000] nv[1]
//  start_e[200000] cur_e[200000] start_v[100000] cur_v[100000]
//  bsum_e[256] bsum_v[256]
//  pay_e[1000000] pay_v[1000000] vlist[24640]
#define CNT_E   0
#define CNT_V   (CNT_E + NUM_EDGES)
#define FLAG_V  (CNT_V + NUM_ENT)
#define FLAG_E  (FLAG_V + NUM_ENT)
#define NV_CNT  (FLAG_E + NUM_EDGES)
#define ZERO_N  (NV_CNT + 1)                        // memset span
#define START_E (ZERO_N)
#define CUR_E   (START_E + NUM_EDGES)
#define START_V (CUR_E + NUM_EDGES)
#define CUR_V   (START_V + NUM_ENT)
#define BSUM_E  (CUR_V + NUM_ENT)
#define BSUM_V  (BSUM_E + 256)
#define PAY_E   (BSUM_V + 256)
#define PAY_V   (PAY_E + NNZ)
#define VLIST   (PAY_V + NNZ)

// ---------------------------------------------------------------------------
// GEMM fused with lorentz: Y = lorentz(X @ W^T + b).
// Block 256 thr, tile 128 rows x 128 cols, K in 4 chunks of 32.
// Per thread: 8 rows x 8 cols. LDS 33.8 KB -> 4 blocks/CU (vs 2 before).
// Stride 132 keeps float4 alignment and caps staging-write conflicts at 4-way.
__global__ __launch_bounds__(256, 4) void k_gemm_lorentz(const float* __restrict__ X,
                                                         const float* __restrict__ W,
                                                         const float* __restrict__ bias,
                                                         const float* __restrict__ scale_p,
                                                         float* __restrict__ Y) {
    __shared__ float smem[2 * 32 * 132];            // 33792 B
    float* Xs = smem;                               // [32][132] (k-major, rows 0..127)
    float* Ws = smem + 32 * 132;                    // [32][132] (k-major, cols 0..127)
    float* Ps = Ws;                                 // [128][17] aliased (post-compute)
    float* Y0 = Xs;                                 // [128]     aliased
    float* Ss = Xs + 128;                           // [128]
    float* Ts = Xs + 256;                           // [128]

    const int t = threadIdx.x;
    const int row0 = blockIdx.x * 128;
    const int tx = t & 15, ty = t >> 4;
    const int j0 = tx * 8;          // 8 output cols per thread
    const int r0 = ty * 8;          // 8 rows per thread
    const float4* X4 = (const float4*)X;
    const float4* W4 = (const float4*)W;

    float acc[8][8];
#pragma unroll
    for (int i = 0; i < 8; ++i)
#pragma unroll
        for (int j = 0; j < 8; ++j) acc[i][j] = 0.f;

    for (int kc = 0; kc < 4; ++kc) {
        // stage X chunk (128 rows x 32 k) and W chunk (128 cols x 32 k)
#pragma unroll
        for (int i = 0; i < 4; ++i) {
            int q = t + 256 * i;                    // 0..1023
            int r = q >> 3, k4 = q & 7;
            int gr = row0 + r;
            float4 xv = make_float4(0.f, 0.f, 0.f, 0.f);
            if (gr < NUM_ENT) xv = X4[gr * 32 + kc * 8 + k4];
            float4 wv = W4[r * 32 + kc * 8 + k4];
            int kb = k4 * 4;
            Xs[(kb + 0) * 132 + r] = xv.x; Xs[(kb + 1) * 132 + r] = xv.y;
            Xs[(kb + 2) * 132 + r] = xv.z; Xs[(kb + 3) * 132 + r] = xv.w;
            Ws[(kb + 0) * 132 + r] = wv.x; Ws[(kb + 1) * 132 + r] = wv.y;
            Ws[(kb + 2) * 132 + r] = wv.z; Ws[(kb + 3) * 132 + r] = wv.w;
        }
        __syncthreads();
#pragma unroll 8
        for (int k = 0; k < 32; ++k) {
            float4 xa = *(const float4*)&Xs[k * 132 + r0];
            float4 xb = *(const float4*)&Xs[k * 132 + r0 + 4];
            float4 wa = *(const float4*)&Ws[k * 132 + j0];
            float4 wb = *(const float4*)&Ws[k * 132 + j0 + 4];
            float xr[8] = {xa.x, xa.y, xa.z, xa.w, xb.x, xb.y, xb.z, xb.w};
            float wr[8] = {wa.x, wa.y, wa.z, wa.w, wb.x, wb.y, wb.z, wb.w};
#pragma unroll
            for (int i = 0; i < 8; ++i)
#pragma unroll
                for (int j = 0; j < 8; ++j)
                    acc[i][j] = fmaf(xr[i], wr[j], acc[i][j]);
        }
        __syncthreads();
    }

    // epilogue: bias + per-row spatial sqnorm partials (LDS now reusable)
    const float4* b4 = (const float4*)bias;
    float4 bb0 = b4[tx * 2], bb1 = b4[tx * 2 + 1];
    float bj[8] = {bb0.x, bb0.y, bb0.z, bb0.w, bb1.x, bb1.y, bb1.z, bb1.w};
#pragma unroll
    for (int i = 0; i < 8; ++i) {
        float p = 0.f;
#pragma unroll
        for (int j = 0; j < 8; ++j) {
            float yv = acc[i][j] + bj[j];
            acc[i][j] = yv;
            p += yv * yv;
        }
        if (tx == 0) {                      // exclude time col, save col-0
            p -= acc[i][0] * acc[i][0];
            Y0[r0 + i] = acc[i][0];
        }
        Ps[(r0 + i) * 17 + tx] = p;
    }
    __syncthreads();
    if (t < 128) {
        float sq = 0.f;
#pragma unroll
        for (int jj = 0; jj < 16; ++jj) sq += Ps[t * 17 + jj];
        float es = expf(scale_p[0]);
        float y0 = Y0[t];
        float time = es / (1.f + expf(-y0)) + 1.1f;
        Ss[t] = sqrtf((time * time - 1.f) / fmaxf(sq, 1e-8f));
        Ts[t] = time;
    }
    __syncthreads();
    float4* Y4 = (float4*)Y;
#pragma unroll
    for (int i = 0; i < 8; ++i) {
        int gr = row0 + r0 + i;
        if (gr >= NUM_ENT) continue;
        float s = Ss[r0 + i], tm = Ts[r0 + i];
        float4 o0, o1;
        o0.x = (tx == 0) ? tm : acc[i][0] * s;
        o0.y = acc[i][1] * s; o0.z = acc[i][2] * s; o0.w = acc[i][3] * s;
        o1.x = acc[i][4] * s; o1.y = acc[i][5] * s;
        o1.z = acc[i][6] * s; o1.w = acc[i][7] * s;
        Y4[gr * 32 + tx * 2]     = o0;
        Y4[gr * 32 + tx * 2 + 1] = o1;
    }
}

// ---------------------------------------------------------------------------
// Flag + dedup + compact the entities actually read by the output stage.
__global__ __launch_bounds__(256) void k_flagv(const int* __restrict__ e1,
                                               const int* __restrict__ e2,
                                               const int* __restrict__ e3,
                                               const int* __restrict__ e4,
                                               const int* __restrict__ e5,
                                               const int* __restrict__ e6,
                                               int* __restrict__ flag_v,
                                               int* __restrict__ vlist,
                                               int* __restrict__ nv) {
    int i = blockIdx.x * 256 + threadIdx.x;
    if (i >= BATCH) return;
    int idx[6] = {e1[i], e2[i], e3[i], e4[i], e5[i], e6[i]};
#pragma unroll
    for (int k = 0; k < 6; ++k) {
        int v = idx[k];
        if (atomicExch(&flag_v[v], 1) == 0)
            vlist[atomicAdd(nv, 1)] = v;
    }
}

// Histogram. cnt_e: all contributors. cnt_v + flag_e: only for flagged verts.
__global__ __launch_bounds__(256) void k_hist(const int* __restrict__ edges,
                                              const int* __restrict__ vertex,
                                              const int* __restrict__ flag_v,
                                              int* __restrict__ cnt_e,
                                              int* __restrict__ cnt_v,
                                              int* __restrict__ flag_e) {
    int i = blockIdx.x * 256 + threadIdx.x;
    if (i >= NNZ) return;
    int v = vertex[i], e = edges[i];
    atomicAdd(&cnt_e[e], 1);
    if (flag_v[v]) {
        atomicAdd(&cnt_v[v], 1);
        flag_e[e] = 1;               // racy store of 1: fine
    }
}

// Block-level exclusive scan: 1024 elems/block (256 thr x 4).
__global__ __launch_bounds__(256) void k_scan_block(const int* __restrict__ cnt,
                                                    int* __restrict__ out,
                                                    int* __restrict__ bsum, int N) {
    __shared__ int lds[256];
    int t = threadIdx.x;
    int base = blockIdx.x * 1024 + t * 4;
    int a[4];
#pragma unroll
    for (int j = 0; j < 4; ++j) a[j] = (base + j < N) ? cnt[base + j] : 0;
    int local = a[0] + a[1] + a[2] + a[3];
    lds[t] = local;
    __syncthreads();
    for (int off = 1; off < 256; off <<= 1) {
        int add = (t >= off) ? lds[t - off] : 0;
        __syncthreads();
        if (t >= off) lds[t] += add;
        __syncthreads();
    }
    int excl = lds[t] - local;
    if (t == 255) bsum[blockIdx.x] = lds[255];
    int s = excl;
#pragma unroll
    for (int j = 0; j < 4; ++j) {
        if (base + j < N) out[base + j] = s;
        s += a[j];
    }
}

__global__ __launch_bounds__(256) void k_scan_top(int* __restrict__ bs, int nb) {
    __shared__ int lds[256];
    int t = threadIdx.x;
    int v = (t < nb) ? bs[t] : 0;
    lds[t] = v;
    __syncthreads();
    for (int off = 1; off < 256; off <<= 1) {
        int add = (t >= off) ? lds[t - off] : 0;
        __syncthreads();
        if (t >= off) lds[t] += add;
        __syncthreads();
    }
    if (t < nb) bs[t] = lds[t] - v;
}

__global__ __launch_bounds__(256) void k_scan_add(int* __restrict__ out,
                                                  int* __restrict__ cur,
                                                  const int* __restrict__ bsum, int N) {
    int i = blockIdx.x * 256 + threadIdx.x;
    if (i >= N) return;
    int v = out[i] + bsum[i >> 10];
    out[i] = v;
    cur[i] = v;
}

// Fill payload arrays (gated on demand flags). pay_e packs (vertex<<9)|ty.
__global__ __launch_bounds__(256) void k_fill(const int* __restrict__ edges,
                                              const int* __restrict__ vertex,
                                              const int* __restrict__ tyi,
                                              const int* __restrict__ flag_e,
                                              const int* __restrict__ flag_v,
                                              int* __restrict__ cur_e,
                                              int* __restrict__ cur_v,
                                              int* __restrict__ pay_e,
                                              int* __restrict__ pay_v) {
    int i = blockIdx.x * 256 + threadIdx.x;
    if (i >= NNZ) return;
    int v = vertex[i], e = edges[i], tt = tyi[i];
    if (flag_e[e]) {
        int p = atomicAdd(&cur_e[e], 1);
        pay_e[p] = (v << 9) | tt;
    }
    if (flag_v[v]) {
        int q = atomicAdd(&cur_v[v], 1);
        pay_v[q] = e;
    }
}

// ---------------------------------------------------------------------------
// Xe[e] = sum over contributors (Xl[v] - Ty[tt]), flagged edges only.
// 32 lanes per edge, float4/lane.
__global__ __launch_bounds__(256) void k_gatherE(const float* __restrict__ Xl,
                                                 const float* __restrict__ Ty,
                                                 const int* __restrict__ flag_e,
                                                 const int* __restrict__ start_e,
                                                 const int* __restrict__ cnt_e,
                                                 const int* __restrict__ pay_e,
                                                 float* __restrict__ Xe) {
    int tid = blockIdx.x * 256 + threadIdx.x;
    int e = tid >> 5, l = tid & 31;
    if (e >= NUM_EDGES) return;
    if (!flag_e[e]) return;
    int s = start_e[e], n = cnt_e[e];
    const float4* Xl4 = (const float4*)Xl;
    const float4* Ty4 = (const float4*)Ty;
    float4 acc = make_float4(0.f, 0.f, 0.f, 0.f);
    for (int k = 0; k < n; ++k) {
        int pe = pay_e[s + k];
        int v = pe >> 9, tt = pe & 511;
        float4 a = Xl4[v * 32 + l];
        float4 c = Ty4[tt * 32 + l];
        acc.x += a.x - c.x; acc.y += a.y - c.y;
        acc.z += a.z - c.z; acc.w += a.w - c.w;
    }
    ((float4*)Xe)[e * 32 + l] = acc;
}

// ---------------------------------------------------------------------------
// For flagged vertices only: Xv gather + E_e = logmap0(eps*Xv + Xl) + row-0
// fixup, in place in Xl. One wave per flagged vertex (via vlist).
__global__ __launch_bounds__(256) void k_gatherV_final(float* __restrict__ XlEe,
                                                       const float* __restrict__ Xe,
                                                       const int* __restrict__ start_v,
                                                       const int* __restrict__ cnt_v,
                                                       const int* __restrict__ pay_v,
                                                       const int* __restrict__ vlist,
                                                       const int* __restrict__ nv_p,
                                                       const float* __restrict__ eps_p) {
    int gid = blockIdx.x * 256 + threadIdx.x;
    int idx = gid >> 6, lane = gid & 63;
    if (idx >= nv_p[0]) return;
    int w = vlist[idx];
    int s = start_v[w], n = cnt_v[w];
    float sa = 0.f, sb = 0.f;
    for (int k = 0; k < n; ++k) {
        int e = pay_v[s + k];
        sa += Xe[e * 128 + lane];
        sb += Xe[e * 128 + 64 + lane];
    }
    float eps = eps_p[0];
    float xa = fmaf(eps, sa, XlEe[w * 128 + lane]);
    float xb = fmaf(eps, sb, XlEe[w * 128 + 64 + lane]);
    float x0 = __shfl(xa, 0, 64);
    float sq = xa * xa + xb * xb;
#pragma unroll
    for (int off = 32; off > 0; off >>= 1) sq += __shfl_xor(sq, off, 64);
    sq = fmaxf(sq - x0 * x0, 0.f);
    float ynorm = fmaxf(sqrtf(sq), 1e-8f);
    float theta = fmaxf(x0, 1.f + 1e-7f);
    float fac = logf(theta + sqrtf(theta * theta - 1.f)) / ynorm;  // arccosh
    float oa = (lane == 0) ? 0.f : xa * fac;
    float ob = xb * fac;
    if (w == 0) { oa = 1.f; ob = 1.f; }
    XlEe[w * 128 + lane]      = oa;
    XlEe[w * 128 + 64 + lane] = ob;
}

// ---------------------------------------------------------------------------
// out[b] = sum_j prod(E_e[e1..e6][j]) * R_e[r_idx][j]. Wave per b.
__global__ __launch_bounds__(256) void k_out(const float* __restrict__ Ee,
                                             const float* __restrict__ R,
                                             const int* __restrict__ r_idx,
                                             const int* __restrict__ e1,
                                             const int* __restrict__ e2,
                                             const int* __restrict__ e3,
                                             const int* __restrict__ e4,
                                             const int* __restrict__ e5,
                                             const int* __restrict__ e6,
                                             float* __restrict__ out) {
    int gid = blockIdx.x * 256 + threadIdx.x;
    int b = gid >> 6, lane = gid & 63;
    if (b >= BATCH) return;
    int i1 = e1[b], i2 = e2[b], i3 = e3[b], i4 = e4[b], i5 = e5[b], i6 = e6[b];
    int rr = r_idx[b];
    float pa = Ee[i1 * 128 + lane] * Ee[i2 * 128 + lane] * Ee[i3 * 128 + lane]
             * Ee[i4 * 128 + lane] * Ee[i5 * 128 + lane] * Ee[i6 * 128 + lane];
    float pb = Ee[i1 * 128 + 64 + lane] * Ee[i2 * 128 + 64 + lane] * Ee[i3 * 128 + 64 + lane]
             * Ee[i4 * 128 + 64 + lane] * Ee[i5 * 128 + 64 + lane] * Ee[i6 * 128 + 64 + lane];
    float ra = (rr == 0) ? 1.f : R[rr * 128 + lane];
    float rb = (rr == 0) ? 1.f : R[rr * 128 + 64 + lane];
    float s = pa * ra + pb * rb;
#pragma unroll
    for (int off = 32; off > 0; off >>= 1) s += __shfl_xor(s, off, 64);
    if (lane == 0) out[b] = s;
}

// ---------------------------------------------------------------------------
extern "C" void kernel_launch(void* const* d_in, const int* in_sizes, int n_in,
                              void* d_out, int out_size, void* d_ws, size_t ws_size,
                              hipStream_t stream) {
    const float* emb_E     = (const float*)d_in[0];
    const float* emb_R     = (const float*)d_in[1];
    const float* emb_ty    = (const float*)d_in[2];
    const float* lin_W     = (const float*)d_in[3];
    const float* lin_b     = (const float*)d_in[4];
    const float* lin_scale = (const float*)d_in[5];
    const float* eps       = (const float*)d_in[6];
    const int* r_idx  = (const int*)d_in[8];
    const int* e1     = (const int*)d_in[9];
    const int* e2     = (const int*)d_in[10];
    const int* e3     = (const int*)d_in[11];
    const int* e4     = (const int*)d_in[12];
    const int* e5     = (const int*)d_in[13];
    const int* e6     = (const int*)d_in[14];
    const int* vertex = (const int*)d_in[15];
    const int* edges  = (const int*)d_in[16];
    const int* tyi    = (const int*)d_in[17];

    float* ws = (float*)d_ws;
    float* Xl = ws + XL_OFF;   // 100000 x 128, becomes E_e in place
    float* Xe = ws + XE_OFF;   // 200000 x 128
    int*   ib = (int*)(ws + INT_OFF);
    int* cnt_e   = ib + CNT_E;
    int* cnt_v   = ib + CNT_V;
    int* flag_v  = ib + FLAG_V;
    int* flag_e  = ib + FLAG_E;
    int* nv      = ib + NV_CNT;
    int* start_e = ib + START_E;
    int* cur_e   = ib + CUR_E;
    int* start_v = ib + START_V;
    int* cur_v   = ib + CUR_V;
    int* bsum_e  = ib + BSUM_E;
    int* bsum_v  = ib + BSUM_V;
    int* pay_e   = ib + PAY_E;
    int* pay_v   = ib + PAY_V;
    int* vlist   = ib + VLIST;

    // zero cnt_e|cnt_v|flag_v|flag_e|nv in one shot
    hipMemsetAsync(cnt_e, 0, (size_t)ZERO_N * sizeof(int), stream);

    const int NBE = (NUM_EDGES + 1023) / 1024;   // 196
    const int NBV = (NUM_ENT  + 1023) / 1024;    // 98

    k_flagv<<<(BATCH + 255) / 256, 256, 0, stream>>>(e1, e2, e3, e4, e5, e6,
                                                     flag_v, vlist, nv);
    k_hist<<<(NNZ + 255) / 256, 256, 0, stream>>>(edges, vertex, flag_v,
                                                  cnt_e, cnt_v, flag_e);
    k_scan_block<<<NBE, 256, 0, stream>>>(cnt_e, start_e, bsum_e, NUM_EDGES);
    k_scan_block<<<NBV, 256, 0, stream>>>(cnt_v, start_v, bsum_v, NUM_ENT);
    k_scan_top<<<1, 256, 0, stream>>>(bsum_e, NBE);
    k_scan_top<<<1, 256, 0, stream>>>(bsum_v, NBV);
    k_scan_add<<<(NUM_EDGES + 255) / 256, 256, 0, stream>>>(start_e, cur_e, bsum_e, NUM_EDGES);
    k_scan_add<<<(NUM_ENT + 255) / 256, 256, 0, stream>>>(start_v, cur_v, bsum_v, NUM_ENT);
    k_fill<<<(NNZ + 255) / 256, 256, 0, stream>>>(edges, vertex, tyi, flag_e, flag_v,
                                                  cur_e, cur_v, pay_e, pay_v);

    k_gemm_lorentz<<<(NUM_ENT + 127) / 128, 256, 0, stream>>>(emb_E, lin_W, lin_b,
                                                              lin_scale, Xl);
    k_gatherE<<<(NUM_EDGES * 32) / 256, 256, 0, stream>>>(Xl, emb_ty, flag_e,
                                                          start_e, cnt_e, pay_e, Xe);
    k_gatherV_final<<<(BATCH * 6 * 64) / 256, 256, 0, stream>>>(Xl, Xe, start_v, cnt_v,
                                                                pay_v, vlist, nv, eps);
    k_out<<<(BATCH * 64) / 256, 256, 0, stream>>>(Xl, emb_R, r_idx,
                                                  e1, e2, e3, e4, e5, e6,
                                                  (float*)d_out);
}